// Round 4
// baseline (1830.028 us; speedup 1.0000x reference)
//
#include <hip/hip_runtime.h>
#include <hip/hip_cooperative_groups.h>

namespace cg = cooperative_groups;

// WaveCell: single persistent cooperative kernel. 16 chunks x 16 time steps,
// grid.sync() between chunks. Each block owns a 24x24 tile, computes on a
// 56x56 extended region in LDS ping-pong buffers; halo patches reload
// y(t-1)/y(t-2) from `out` at chunk boundaries, interior state persists in
// registers. Inner loop identical to the verified round-3 kernel.

#define NXg 192
#define NYg 192
#define BATCH 4
#define TSTEPS 256
#define CELLS (NXg * NYg)

#define TS 24                   // output tile side
#define KSTEP 16                // time steps per chunk
#define NCHUNK (TSTEPS / KSTEP) // 16
#define EXT 56                  // TS + 2*KSTEP
#define GROW 14                 // float4 groups per row (EXT/4)
#define NP (EXT * GROW)         // 784 patches per block
#define LROWS (EXT + 2)         // +1 guard row top/bottom
#define LPITCH 64               // dwords; 4 guard cols left, 4 right
#define LSZ (LROWS * LPITCH)    // 3712 dwords = 14.5 KB per buffer
#define NTHREADS 512
#define NPT 2                   // patches per thread

#define SRC_X 96
#define SRC_Y 32

__global__ __launch_bounds__(NTHREADS) void wave_persist_kernel(
    const float* __restrict__ cgp, const float* __restrict__ bgp,
    const float* __restrict__ x, float* __restrict__ out) {
  cg::grid_group grid = cg::this_grid();

  __shared__ float buf0[LSZ];
  __shared__ float buf1[LSZ];

  const int tid = threadIdx.x;
  const int bcol = blockIdx.x;  // 0..7
  const int brow = blockIdx.y;  // 0..7
  const int bb = blockIdx.z;    // 0..3
  const int r0 = brow * TS - KSTEP;
  const int c0 = bcol * TS - KSTEP;
  const int obase = bb * TSTEPS * CELLS;
  const float inv_h2 = (float)(1.0 / (2.0 * 1.01 * 1.01 * 1.0e-3 * 1.0e-3));

  // Zero both LDS buffers ONCE (guard ring stays 0 forever; data cells are
  // always rewritten before being read).
  {
    float4 z = make_float4(0.f, 0.f, 0.f, 0.f);
    float4* p0 = (float4*)buf0;
    float4* p1 = (float4*)buf1;
    for (int i = tid; i < LSZ / 4; i += NTHREADS) {
      p0[i] = z;
      p1[i] = z;
    }
  }

  // Per-patch static state (computed once).
  float4 yc[NPT], yp[NPT], ai[NPT], cf[NPT], cs[NPT], sm[NPT];
  int loff[NPT], gofs[NPT];
  bool act[NPT], til[NPT], ref[NPT];

#pragma unroll
  for (int it = 0; it < NPT; ++it) {
    const int p = tid + it * NTHREADS;
    const float4 z = make_float4(0.f, 0.f, 0.f, 0.f);
    yc[it] = z; yp[it] = z; ai[it] = z; cf[it] = z; cs[it] = z; sm[it] = z;
    loff[it] = LPITCH + 4; gofs[it] = 0; til[it] = false; ref[it] = false;
    act[it] = (p < NP);
    if (act[it]) {
      const int lr = p / GROW;
      const int lg = p % GROW;
      loff[it] = (lr + 1) * LPITCH + 4 + lg * 4;
      const int gr = r0 + lr;
      const int gc = c0 + lg * 4;  // multiple of 4; groups never straddle domain edge
      til[it] = (lr >= KSTEP && lr < KSTEP + TS && lg >= 4 && lg < 10);
      if (gr >= 0 && gr < NXg && gc >= 0 && gc < NYg) {
        const int gi = gr * NYg + gc;
        gofs[it] = gi;
        ref[it] = !til[it];  // in-domain halo patch: reload at chunk bounds
        float4 cv = *(const float4*)(cgp + gi);
        float4 bv = *(const float4*)(bgp + gi);
        ai[it].x = 1.0f / (1.0e6f + 500.0f * bv.x);
        ai[it].y = 1.0f / (1.0e6f + 500.0f * bv.y);
        ai[it].z = 1.0f / (1.0e6f + 500.0f * bv.z);
        ai[it].w = 1.0f / (1.0e6f + 500.0f * bv.w);
        cf[it].x = 1.0e6f - 500.0f * bv.x;
        cf[it].y = 1.0e6f - 500.0f * bv.y;
        cf[it].z = 1.0e6f - 500.0f * bv.z;
        cf[it].w = 1.0e6f - 500.0f * bv.w;
        cs[it].x = cv.x * cv.x;
        cs[it].y = cv.y * cv.y;
        cs[it].z = cv.z * cv.z;
        cs[it].w = cv.w * cv.w;
        if (gr == SRC_X && SRC_Y >= gc && SRC_Y < gc + 4) {
          ((float*)&sm[it])[SRC_Y - gc] = 1.0f;
        }
      }
    }
  }

  __syncthreads();  // LDS zero-fill complete; chunk 0 starts from all-zero field

  float* ping = buf0;
  float* pong = buf1;

  for (int chunk = 0; chunk < NCHUNK; ++chunk) {
    const int t0 = chunk * KSTEP;

    if (chunk > 0) {
      __threadfence();  // release our tile's stores of steps t0-1, t0-2
      grid.sync();
      __threadfence();  // acquire other XCDs' stores
      // Reload halo patches' y(t-1), y(t-2); interior register state is valid
      // and buf0 (== ping here, 16 even steps) already holds interior y(t-1).
#pragma unroll
      for (int it = 0; it < NPT; ++it) {
        if (ref[it]) {
          yc[it] = *(const float4*)(out + obase + (t0 - 1) * CELLS + gofs[it]);
          yp[it] = *(const float4*)(out + obase + (t0 - 2) * CELLS + gofs[it]);
        }
      }
#pragma unroll
      for (int it = 0; it < NPT; ++it) {
        if (ref[it]) *(float4*)&ping[loff[it]] = yc[it];
      }
      __syncthreads();
    }

    // Source samples for this chunk.
    float xs[KSTEP];
    {
      const float4* xp = (const float4*)(x + bb * TSTEPS + t0);
      float4 a0 = xp[0], a1 = xp[1], a2 = xp[2], a3 = xp[3];
      xs[0] = a0.x; xs[1] = a0.y; xs[2] = a0.z; xs[3] = a0.w;
      xs[4] = a1.x; xs[5] = a1.y; xs[6] = a1.z; xs[7] = a1.w;
      xs[8] = a2.x; xs[9] = a2.y; xs[10] = a2.z; xs[11] = a2.w;
      xs[12] = a3.x; xs[13] = a3.y; xs[14] = a3.z; xs[15] = a3.w;
    }

#pragma unroll
    for (int j = 0; j < KSTEP; ++j) {
      const float xt = xs[j];
      float* op = out + obase + (t0 + j) * CELLS;
#pragma unroll
      for (int it = 0; it < NPT; ++it) {
        if (act[it]) {
          const int lo = loff[it];
          float4 up = *(float4*)&ping[lo - LPITCH];
          float4 dn = *(float4*)&ping[lo + LPITCH];
          float4 lq = *(float4*)&ping[lo - 4];   // need only .w
          float4 rq = *(float4*)&ping[lo + 4];   // need only .x
          float4 v1 = yc[it];
          float4 vp = yp[it];
          float4 av = ai[it], fv = cf[it], sv = cs[it], smv = sm[it];
          float4 val;
          {
            float lap = inv_h2 * (up.x + dn.x + lq.w + v1.y - 4.0f * v1.x);
            val.x = av.x * (2.0e6f * v1.x - fv.x * vp.x + sv.x * lap) + smv.x * xt;
          }
          {
            float lap = inv_h2 * (up.y + dn.y + v1.x + v1.z - 4.0f * v1.y);
            val.y = av.y * (2.0e6f * v1.y - fv.y * vp.y + sv.y * lap) + smv.y * xt;
          }
          {
            float lap = inv_h2 * (up.z + dn.z + v1.y + v1.w - 4.0f * v1.z);
            val.z = av.z * (2.0e6f * v1.z - fv.z * vp.z + sv.z * lap) + smv.z * xt;
          }
          {
            float lap = inv_h2 * (up.w + dn.w + v1.z + rq.x - 4.0f * v1.w);
            val.w = av.w * (2.0e6f * v1.w - fv.w * vp.w + sv.w * lap) + smv.w * xt;
          }
          yp[it] = v1;
          yc[it] = val;
          *(float4*)&pong[lo] = val;
          if (til[it]) *(float4*)(op + gofs[it]) = val;
        }
      }
      __syncthreads();
      float* tmp = ping; ping = pong; pong = tmp;
    }
  }
}

extern "C" void kernel_launch(void* const* d_in, const int* in_sizes, int n_in,
                              void* d_out, int out_size, void* d_ws,
                              size_t ws_size, hipStream_t stream) {
  const float* x = (const float*)d_in[0];  // [B, T, 1]
  const float* c = (const float*)d_in[1];  // [192,192]
  const float* b = (const float*)d_in[2];  // [192,192]
  float* out = (float*)d_out;              // [B, T, 192, 192]

  void* args[] = {(void*)&c, (void*)&b, (void*)&x, (void*)&out};
  dim3 grid(NXg / TS, NYg / TS, BATCH);  // 8 x 8 x 4 = 256 blocks
  dim3 block(NTHREADS, 1, 1);
  (void)hipLaunchCooperativeKernel((const void*)wave_persist_kernel, grid,
                                   block, args, 0, stream);
}

// Round 5
// 327.173 us; speedup vs baseline: 5.5935x; 5.5935x over previous
//
#include <hip/hip_runtime.h>

// WaveCell: 16 launches x 16 time steps, temporal blocking with 8-wide
// register patches. Each thread owns 8 contiguous cells (2 float4) of a
// 56x56 extended region; left/right stencil neighbors come from wave
// shuffles of register state, up/down from LDS ping-pong buffers.
// Lane mapping is row-aligned (8 lanes/row: 7 active + 1 zero lane), so the
// inner loop has NO predication: out-of-domain / pad cells self-zero via
// zero coefficients, and guard reads return 0 (shrinking-region invariant
// makes edge garbage unobservable).

#define NXg 192
#define NYg 192
#define BATCH 4
#define TSTEPS 256
#define CELLS (NXg * NYg)

#define TS 24                   // output tile side
#define KSTEP 16                // time steps per launch
#define EXT 56                  // TS + 2*KSTEP
#define LROWS (EXT + 2)         // guard row top + bottom = 58
#define LPITCH 68               // dwords/row: 4 guard | 56 data | 8 guard; %32==4 spreads banks
#define LSZ (LROWS * LPITCH)    // 3944 dwords = 15.4 KB per buffer
#define NTHREADS 448            // 56 rows x 8 lanes/row = 7 waves

#define SRC_X 96
#define SRC_Y 32

__global__ __launch_bounds__(NTHREADS) void wave_tile_kernel(
    const float* __restrict__ cgp, const float* __restrict__ bgp,
    const float* __restrict__ x, float* __restrict__ out, int t0) {
  __shared__ float buf0[LSZ];
  __shared__ float buf1[LSZ];

  const int tid = threadIdx.x;
  const int lr = tid >> 3;      // local row 0..55
  const int lg = tid & 7;       // 8-wide group in row; lg==7 is the zero lane
  const int bcol = blockIdx.x;  // 0..7
  const int brow = blockIdx.y;  // 0..7
  const int bb = blockIdx.z;    // 0..3
  const int r0 = brow * TS - KSTEP;
  const int c0 = bcol * TS - KSTEP;
  const int obase = bb * TSTEPS * CELLS;
  const float inv_h2 = (float)(1.0 / (2.0 * 1.01 * 1.01 * 1.0e-3 * 1.0e-3));

  // Zero both LDS buffers (guard rows/cols must read 0; data is rewritten
  // by the scatter / every step's full pong write before any read).
  {
    float4 z = make_float4(0.f, 0.f, 0.f, 0.f);
    float4* p0 = (float4*)buf0;
    float4* p1 = (float4*)buf1;
    for (int i = tid; i < LSZ / 4; i += NTHREADS) {
      p0[i] = z;
      p1[i] = z;
    }
  }

  // Source samples for this chunk (t0 is a multiple of 16).
  float xs[KSTEP];
  {
    const float4* xp = (const float4*)(x + bb * TSTEPS + t0);
    float4 a0 = xp[0], a1 = xp[1], a2 = xp[2], a3 = xp[3];
    xs[0] = a0.x; xs[1] = a0.y; xs[2] = a0.z; xs[3] = a0.w;
    xs[4] = a1.x; xs[5] = a1.y; xs[6] = a1.z; xs[7] = a1.w;
    xs[8] = a2.x; xs[9] = a2.y; xs[10] = a2.z; xs[11] = a2.w;
    xs[12] = a3.x; xs[13] = a3.y; xs[14] = a3.z; xs[15] = a3.w;
  }

  // LDS dword offset of this thread's 8 cells (16B aligned).
  const int lo = (lr + 1) * LPITCH + 4 + 8 * lg;  // lg==7 -> right guard zone

  const int gr = r0 + lr;
  const int gc = c0 + 8 * lg;  // multiple of 8; never straddles domain edge
  const bool id = (lg < 7) && (gr >= 0) && (gr < NXg) && (gc >= 0) && (gc < NYg);
  const bool til = (lr >= KSTEP) && (lr < KSTEP + TS) && (lg >= 2) && (lg < 5);
  const int gofs = id ? (gr * NYg + gc) : 0;

  const float4 z4 = make_float4(0.f, 0.f, 0.f, 0.f);
  float4 yc0 = z4, yc1 = z4, yp0 = z4, yp1 = z4;
  float4 ai0 = z4, ai1 = z4, cf0 = z4, cf1 = z4, cs0 = z4, cs1 = z4;
  float4 sm0 = z4, sm1 = z4;

  if (id) {
    float4 cv0 = *(const float4*)(cgp + gofs);
    float4 cv1 = *(const float4*)(cgp + gofs + 4);
    float4 bv0 = *(const float4*)(bgp + gofs);
    float4 bv1 = *(const float4*)(bgp + gofs + 4);
    ai0.x = 1.0f / (1.0e6f + 500.0f * bv0.x);
    ai0.y = 1.0f / (1.0e6f + 500.0f * bv0.y);
    ai0.z = 1.0f / (1.0e6f + 500.0f * bv0.z);
    ai0.w = 1.0f / (1.0e6f + 500.0f * bv0.w);
    ai1.x = 1.0f / (1.0e6f + 500.0f * bv1.x);
    ai1.y = 1.0f / (1.0e6f + 500.0f * bv1.y);
    ai1.z = 1.0f / (1.0e6f + 500.0f * bv1.z);
    ai1.w = 1.0f / (1.0e6f + 500.0f * bv1.w);
    cf0.x = 1.0e6f - 500.0f * bv0.x;
    cf0.y = 1.0e6f - 500.0f * bv0.y;
    cf0.z = 1.0e6f - 500.0f * bv0.z;
    cf0.w = 1.0e6f - 500.0f * bv0.w;
    cf1.x = 1.0e6f - 500.0f * bv1.x;
    cf1.y = 1.0e6f - 500.0f * bv1.y;
    cf1.z = 1.0e6f - 500.0f * bv1.z;
    cf1.w = 1.0e6f - 500.0f * bv1.w;
    cs0.x = cv0.x * cv0.x; cs0.y = cv0.y * cv0.y;
    cs0.z = cv0.z * cv0.z; cs0.w = cv0.w * cv0.w;
    cs1.x = cv1.x * cv1.x; cs1.y = cv1.y * cv1.y;
    cs1.z = cv1.z * cv1.z; cs1.w = cv1.w * cv1.w;
    if (t0 > 0) {
      yc0 = *(const float4*)(out + obase + (t0 - 1) * CELLS + gofs);
      yc1 = *(const float4*)(out + obase + (t0 - 1) * CELLS + gofs + 4);
      yp0 = *(const float4*)(out + obase + (t0 - 2) * CELLS + gofs);
      yp1 = *(const float4*)(out + obase + (t0 - 2) * CELLS + gofs + 4);
    }
    if (gr == SRC_X) {
      sm0.x = (gc + 0 == SRC_Y) ? 1.0f : 0.0f;
      sm0.y = (gc + 1 == SRC_Y) ? 1.0f : 0.0f;
      sm0.z = (gc + 2 == SRC_Y) ? 1.0f : 0.0f;
      sm0.w = (gc + 3 == SRC_Y) ? 1.0f : 0.0f;
      sm1.x = (gc + 4 == SRC_Y) ? 1.0f : 0.0f;
      sm1.y = (gc + 5 == SRC_Y) ? 1.0f : 0.0f;
      sm1.z = (gc + 6 == SRC_Y) ? 1.0f : 0.0f;
      sm1.w = (gc + 7 == SRC_Y) ? 1.0f : 0.0f;
    }
  }

  __syncthreads();  // zero-fill complete before scatter

  // Scatter y(t-1): all lanes write (inactive lanes write 0 into guard).
  *(float4*)&buf0[lo] = yc0;
  *(float4*)&buf0[lo + 4] = yc1;
  __syncthreads();

  float* ping = buf0;
  float* pong = buf1;

#pragma unroll
  for (int j = 0; j < KSTEP; ++j) {
    const float xt = xs[j];
    float* op = out + obase + (t0 + j) * CELLS;

    // Left/right edge neighbors from register state of adjacent lanes.
    float lqw = __shfl_up(yc1.w, 1);
    lqw = (lg == 0) ? 0.0f : lqw;       // row's left guard is 0
    float rqx = __shfl_down(yc0.x, 1);  // lg==6 pulls zero lane lg==7 -> 0

    float4 up0 = *(float4*)&ping[lo - LPITCH];
    float4 up1 = *(float4*)&ping[lo - LPITCH + 4];
    float4 dn0 = *(float4*)&ping[lo + LPITCH];
    float4 dn1 = *(float4*)&ping[lo + LPITCH + 4];

    float4 val0, val1;
    {
      float lap = inv_h2 * (up0.x + dn0.x + lqw + yc0.y - 4.0f * yc0.x);
      val0.x = ai0.x * (2.0e6f * yc0.x - cf0.x * yp0.x + cs0.x * lap) + sm0.x * xt;
    }
    {
      float lap = inv_h2 * (up0.y + dn0.y + yc0.x + yc0.z - 4.0f * yc0.y);
      val0.y = ai0.y * (2.0e6f * yc0.y - cf0.y * yp0.y + cs0.y * lap) + sm0.y * xt;
    }
    {
      float lap = inv_h2 * (up0.z + dn0.z + yc0.y + yc0.w - 4.0f * yc0.z);
      val0.z = ai0.z * (2.0e6f * yc0.z - cf0.z * yp0.z + cs0.z * lap) + sm0.z * xt;
    }
    {
      float lap = inv_h2 * (up0.w + dn0.w + yc0.z + yc1.x - 4.0f * yc0.w);
      val0.w = ai0.w * (2.0e6f * yc0.w - cf0.w * yp0.w + cs0.w * lap) + sm0.w * xt;
    }
    {
      float lap = inv_h2 * (up1.x + dn1.x + yc0.w + yc1.y - 4.0f * yc1.x);
      val1.x = ai1.x * (2.0e6f * yc1.x - cf1.x * yp1.x + cs1.x * lap) + sm1.x * xt;
    }
    {
      float lap = inv_h2 * (up1.y + dn1.y + yc1.x + yc1.z - 4.0f * yc1.y);
      val1.y = ai1.y * (2.0e6f * yc1.y - cf1.y * yp1.y + cs1.y * lap) + sm1.y * xt;
    }
    {
      float lap = inv_h2 * (up1.z + dn1.z + yc1.y + yc1.w - 4.0f * yc1.z);
      val1.z = ai1.z * (2.0e6f * yc1.z - cf1.z * yp1.z + cs1.z * lap) + sm1.z * xt;
    }
    {
      float lap = inv_h2 * (up1.w + dn1.w + yc1.z + rqx - 4.0f * yc1.w);
      val1.w = ai1.w * (2.0e6f * yc1.w - cf1.w * yp1.w + cs1.w * lap) + sm1.w * xt;
    }

    yp0 = yc0; yp1 = yc1;
    yc0 = val0; yc1 = val1;

    *(float4*)&pong[lo] = val0;      // lg==7 writes 0 into right guard
    *(float4*)&pong[lo + 4] = val1;

    if (til) {
      *(float4*)(op + gofs) = val0;
      *(float4*)(op + gofs + 4) = val1;
    }

    __syncthreads();
    float* tmp = ping; ping = pong; pong = tmp;
  }
}

extern "C" void kernel_launch(void* const* d_in, const int* in_sizes, int n_in,
                              void* d_out, int out_size, void* d_ws,
                              size_t ws_size, hipStream_t stream) {
  const float* x = (const float*)d_in[0];  // [B, T, 1]
  const float* c = (const float*)d_in[1];  // [192,192]
  const float* b = (const float*)d_in[2];  // [192,192]
  float* out = (float*)d_out;              // [B, T, 192, 192]

  dim3 grid(NXg / TS, NYg / TS, BATCH);  // 8 x 8 x 4 = 256 blocks
  for (int t0 = 0; t0 < TSTEPS; t0 += KSTEP) {
    wave_tile_kernel<<<grid, NTHREADS, 0, stream>>>(c, b, x, out, t0);
  }
}

// Round 6
// 320.289 us; speedup vs baseline: 5.7137x; 1.0215x over previous
//
#include <hip/hip_runtime.h>

// WaveCell: 16 launches x 16 time steps, temporal blocking with 8-wide
// register patches (round-5 structure). Round-6 changes:
//  - global out-stores software-pipelined by one step (issued right AFTER
//    the barrier) so the compiler's vmcnt(0) drain before s_barrier is
//    covered by a full step of LDS/VALU work
//  - prologue global loads issued before LDS zeroing / coefficient math
//  - only guard ROWS are zeroed (side guards are never read from LDS;
//    left/right neighbors come from wave shuffles)

#define NXg 192
#define NYg 192
#define BATCH 4
#define TSTEPS 256
#define CELLS (NXg * NYg)

#define TS 24                   // output tile side
#define KSTEP 16                // time steps per launch
#define EXT 56                  // TS + 2*KSTEP
#define LROWS (EXT + 2)         // guard row top + bottom = 58
#define LPITCH 68               // dwords/row: 4 pad | 56 data | 8 pad; %32==4 spreads banks
#define LSZ (LROWS * LPITCH)
#define NTHREADS 448            // 56 rows x 8 lanes/row = 7 waves

#define SRC_X 96
#define SRC_Y 32

__global__ __launch_bounds__(NTHREADS) void wave_tile_kernel(
    const float* __restrict__ cgp, const float* __restrict__ bgp,
    const float* __restrict__ x, float* __restrict__ out, int t0) {
  __shared__ float buf0[LSZ];
  __shared__ float buf1[LSZ];

  const int tid = threadIdx.x;
  const int lr = tid >> 3;      // local row 0..55
  const int lg = tid & 7;       // 8-wide group in row; lg==7 is the zero lane
  const int bcol = blockIdx.x;  // 0..7
  const int brow = blockIdx.y;  // 0..7
  const int bb = blockIdx.z;    // 0..3
  const int r0 = brow * TS - KSTEP;
  const int c0 = bcol * TS - KSTEP;
  const int obase = bb * TSTEPS * CELLS;
  const float inv_h2 = (float)(1.0 / (2.0 * 1.01 * 1.01 * 1.0e-3 * 1.0e-3));

  const int gr = r0 + lr;
  const int gc = c0 + 8 * lg;  // multiple of 8; never straddles domain edge
  const bool id = (lg < 7) && (gr >= 0) && (gr < NXg) && (gc >= 0) && (gc < NYg);
  const bool til = (lr >= KSTEP) && (lr < KSTEP + TS) && (lg >= 2) && (lg < 5);
  const int gofs = id ? (gr * NYg + gc) : 0;

  const float4 z4 = make_float4(0.f, 0.f, 0.f, 0.f);

  // ---- 1. Issue ALL global loads up front (latency overlaps the rest). ----
  float4 cv0 = z4, cv1 = z4, bv0 = z4, bv1 = z4;
  float4 yc0 = z4, yc1 = z4, yp0 = z4, yp1 = z4;
  if (id) {
    cv0 = *(const float4*)(cgp + gofs);
    cv1 = *(const float4*)(cgp + gofs + 4);
    bv0 = *(const float4*)(bgp + gofs);
    bv1 = *(const float4*)(bgp + gofs + 4);
    if (t0 > 0) {
      yc0 = *(const float4*)(out + obase + (t0 - 1) * CELLS + gofs);
      yc1 = *(const float4*)(out + obase + (t0 - 1) * CELLS + gofs + 4);
      yp0 = *(const float4*)(out + obase + (t0 - 2) * CELLS + gofs);
      yp1 = *(const float4*)(out + obase + (t0 - 2) * CELLS + gofs + 4);
    }
  }
  float xs[KSTEP];
  {
    const float4* xp = (const float4*)(x + bb * TSTEPS + t0);
    float4 a0 = xp[0], a1 = xp[1], a2 = xp[2], a3 = xp[3];
    xs[0] = a0.x; xs[1] = a0.y; xs[2] = a0.z; xs[3] = a0.w;
    xs[4] = a1.x; xs[5] = a1.y; xs[6] = a1.z; xs[7] = a1.w;
    xs[8] = a2.x; xs[9] = a2.y; xs[10] = a2.z; xs[11] = a2.w;
    xs[12] = a3.x; xs[13] = a3.y; xs[14] = a3.z; xs[15] = a3.w;
  }

  // ---- 2. Zero ONLY guard rows (0 and LROWS-1), dwords 4..67, both bufs. --
  // Side guard columns are never read from LDS (shuffles supply them).
  if (tid < 64) {
    const int sel = tid >> 4;  // 0..3
    const int g = tid & 15;    // 16 float4 per guard row
    float* base = (sel & 2) ? buf1 : buf0;
    const int row = (sel & 1) ? (LROWS - 1) : 0;
    *(float4*)&base[row * LPITCH + 4 + 4 * g] = z4;
  }

  // ---- 3. Coefficients (overlaps load latency). ----
  float4 ai0 = z4, ai1 = z4, cf0 = z4, cf1 = z4, cs0 = z4, cs1 = z4;
  float4 sm0 = z4, sm1 = z4;
  if (id) {
    ai0.x = 1.0f / (1.0e6f + 500.0f * bv0.x);
    ai0.y = 1.0f / (1.0e6f + 500.0f * bv0.y);
    ai0.z = 1.0f / (1.0e6f + 500.0f * bv0.z);
    ai0.w = 1.0f / (1.0e6f + 500.0f * bv0.w);
    ai1.x = 1.0f / (1.0e6f + 500.0f * bv1.x);
    ai1.y = 1.0f / (1.0e6f + 500.0f * bv1.y);
    ai1.z = 1.0f / (1.0e6f + 500.0f * bv1.z);
    ai1.w = 1.0f / (1.0e6f + 500.0f * bv1.w);
    cf0.x = 1.0e6f - 500.0f * bv0.x;
    cf0.y = 1.0e6f - 500.0f * bv0.y;
    cf0.z = 1.0e6f - 500.0f * bv0.z;
    cf0.w = 1.0e6f - 500.0f * bv0.w;
    cf1.x = 1.0e6f - 500.0f * bv1.x;
    cf1.y = 1.0e6f - 500.0f * bv1.y;
    cf1.z = 1.0e6f - 500.0f * bv1.z;
    cf1.w = 1.0e6f - 500.0f * bv1.w;
    cs0.x = cv0.x * cv0.x; cs0.y = cv0.y * cv0.y;
    cs0.z = cv0.z * cv0.z; cs0.w = cv0.w * cv0.w;
    cs1.x = cv1.x * cv1.x; cs1.y = cv1.y * cv1.y;
    cs1.z = cv1.z * cv1.z; cs1.w = cv1.w * cv1.w;
    if (gr == SRC_X) {
      sm0.x = (gc + 0 == SRC_Y) ? 1.0f : 0.0f;
      sm0.y = (gc + 1 == SRC_Y) ? 1.0f : 0.0f;
      sm0.z = (gc + 2 == SRC_Y) ? 1.0f : 0.0f;
      sm0.w = (gc + 3 == SRC_Y) ? 1.0f : 0.0f;
      sm1.x = (gc + 4 == SRC_Y) ? 1.0f : 0.0f;
      sm1.y = (gc + 5 == SRC_Y) ? 1.0f : 0.0f;
      sm1.z = (gc + 6 == SRC_Y) ? 1.0f : 0.0f;
      sm1.w = (gc + 7 == SRC_Y) ? 1.0f : 0.0f;
    }
  }

  // ---- 4. Scatter y(t-1) into buf0 (disjoint rows from guard zeroing). ----
  const int lo = (lr + 1) * LPITCH + 4 + 8 * lg;
  *(float4*)&buf0[lo] = yc0;
  *(float4*)&buf0[lo + 4] = yc1;
  __syncthreads();  // single prologue barrier

  float* ping = buf0;
  float* pong = buf1;

  // Pipelined output store state.
  float4 pv0 = z4, pv1 = z4;
  float* pop = out;  // dummy; only used when j>0

#pragma unroll
  for (int j = 0; j < KSTEP; ++j) {
    const float xt = xs[j];
    float* op = out + obase + (t0 + j) * CELLS;

    // Store PREVIOUS step's output now: a full step of work separates this
    // store from the next barrier's vmcnt(0) drain.
    if (j > 0 && til) {
      *(float4*)(pop + gofs) = pv0;
      *(float4*)(pop + gofs + 4) = pv1;
    }

    // Left/right edge neighbors from register state of adjacent lanes.
    float lqw = __shfl_up(yc1.w, 1);
    lqw = (lg == 0) ? 0.0f : lqw;       // row's left edge neighbor is 0
    float rqx = __shfl_down(yc0.x, 1);  // lg==6 pulls zero lane lg==7 -> 0

    float4 up0 = *(float4*)&ping[lo - LPITCH];
    float4 up1 = *(float4*)&ping[lo - LPITCH + 4];
    float4 dn0 = *(float4*)&ping[lo + LPITCH];
    float4 dn1 = *(float4*)&ping[lo + LPITCH + 4];

    float4 val0, val1;
    {
      float lap = inv_h2 * (up0.x + dn0.x + lqw + yc0.y - 4.0f * yc0.x);
      val0.x = ai0.x * (2.0e6f * yc0.x - cf0.x * yp0.x + cs0.x * lap) + sm0.x * xt;
    }
    {
      float lap = inv_h2 * (up0.y + dn0.y + yc0.x + yc0.z - 4.0f * yc0.y);
      val0.y = ai0.y * (2.0e6f * yc0.y - cf0.y * yp0.y + cs0.y * lap) + sm0.y * xt;
    }
    {
      float lap = inv_h2 * (up0.z + dn0.z + yc0.y + yc0.w - 4.0f * yc0.z);
      val0.z = ai0.z * (2.0e6f * yc0.z - cf0.z * yp0.z + cs0.z * lap) + sm0.z * xt;
    }
    {
      float lap = inv_h2 * (up0.w + dn0.w + yc0.z + yc1.x - 4.0f * yc0.w);
      val0.w = ai0.w * (2.0e6f * yc0.w - cf0.w * yp0.w + cs0.w * lap) + sm0.w * xt;
    }
    {
      float lap = inv_h2 * (up1.x + dn1.x + yc0.w + yc1.y - 4.0f * yc1.x);
      val1.x = ai1.x * (2.0e6f * yc1.x - cf1.x * yp1.x + cs1.x * lap) + sm1.x * xt;
    }
    {
      float lap = inv_h2 * (up1.y + dn1.y + yc1.x + yc1.z - 4.0f * yc1.y);
      val1.y = ai1.y * (2.0e6f * yc1.y - cf1.y * yp1.y + cs1.y * lap) + sm1.y * xt;
    }
    {
      float lap = inv_h2 * (up1.z + dn1.z + yc1.y + yc1.w - 4.0f * yc1.z);
      val1.z = ai1.z * (2.0e6f * yc1.z - cf1.z * yp1.z + cs1.z * lap) + sm1.z * xt;
    }
    {
      float lap = inv_h2 * (up1.w + dn1.w + yc1.z + rqx - 4.0f * yc1.w);
      val1.w = ai1.w * (2.0e6f * yc1.w - cf1.w * yp1.w + cs1.w * lap) + sm1.w * xt;
    }

    yp0 = yc0; yp1 = yc1;
    yc0 = val0; yc1 = val1;

    *(float4*)&pong[lo] = val0;      // lg==7 writes 0 into right pad
    *(float4*)&pong[lo + 4] = val1;

    pv0 = val0; pv1 = val1; pop = op;

    __syncthreads();
    float* tmp = ping; ping = pong; pong = tmp;
  }

  // Final step's output store (drains at kernel end).
  if (til) {
    *(float4*)(pop + gofs) = pv0;
    *(float4*)(pop + gofs + 4) = pv1;
  }
}

extern "C" void kernel_launch(void* const* d_in, const int* in_sizes, int n_in,
                              void* d_out, int out_size, void* d_ws,
                              size_t ws_size, hipStream_t stream) {
  const float* x = (const float*)d_in[0];  // [B, T, 1]
  const float* c = (const float*)d_in[1];  // [192,192]
  const float* b = (const float*)d_in[2];  // [192,192]
  float* out = (float*)d_out;              // [B, T, 192, 192]

  dim3 grid(NXg / TS, NYg / TS, BATCH);  // 8 x 8 x 4 = 256 blocks
  for (int t0 = 0; t0 < TSTEPS; t0 += KSTEP) {
    wave_tile_kernel<<<grid, NTHREADS, 0, stream>>>(c, b, x, out, t0);
  }
}